// Round 12
// baseline (203.820 us; speedup 1.0000x reference)
//
#include <hip/hip_runtime.h>
#include <hip/hip_bf16.h>

#define HEADS 4
#define DH    128
#define CIN   256
#define NPIX  16384
#define NB    4
#define HID   512

typedef __attribute__((ext_vector_type(8))) short bf16x8;
typedef __attribute__((ext_vector_type(4))) float f32x4;
typedef __attribute__((ext_vector_type(2))) unsigned u32x2;

__device__ __forceinline__ unsigned short f2bfu(float f) {
    union { __hip_bfloat16 h; unsigned short u; } cv;
    cv.h = __float2bfloat16(f);
    return cv.u;
}

// ---- async global->LDS, 16B per lane --------------------------------------
typedef const __attribute__((address_space(1))) unsigned char* gas_t;
typedef __attribute__((address_space(3))) unsigned char* las_t;
__device__ __forceinline__ void glds16(const void* g, void* s) {
    __builtin_amdgcn_global_load_lds((gas_t)g, (las_t)s, 16, 0, 0);
}
__device__ __forceinline__ unsigned lds_off(const void* p) {
    return (unsigned)(size_t)(las_t)p;
}

// Frag-tile (weights/P/F): 16(row) x 32(k) bf16 = 512 ushorts, lane-major:
// element (row r, k) at us = (r + 16*(k>>3))*8 + (k&7).
// Plain tile (x): 16c x 16n, element (c,n) at us = (n&15)*16 + (c&15).

// ---------------------------------------------------------------------------
// K0a: x[b][c][n] fp32 -> xp plain tiles [b][n16 1024][c16 16][256]
// grid (256, 4, 4), block 256
// ---------------------------------------------------------------------------
__global__ __launch_bounds__(256) void xp_convert(const float* __restrict__ x,
                                                  unsigned short* __restrict__ xp)
{
    __shared__ float tile[64][67];
    const int b = blockIdx.z, c0 = blockIdx.y * 64, n0 = blockIdx.x * 64;
    const int t = threadIdx.x;
    const float* xb = x + ((size_t)b * CIN + c0) * NPIX + n0;
#pragma unroll
    for (int p = 0; p < 4; ++p) {
        const int c = p * 16 + (t >> 4);
        const int n = (t & 15) * 4;
        float4 v = *reinterpret_cast<const float4*>(xb + (size_t)c * NPIX + n);
        tile[c][n + 0] = v.x; tile[c][n + 1] = v.y;
        tile[c][n + 2] = v.z; tile[c][n + 3] = v.w;
    }
    __syncthreads();
    // each thread writes one 16-c row of one tile (32B)
    const int n16l = t >> 6, c16l = (t >> 4) & 3, n_loc = t & 15;
    unsigned short u16[16];
#pragma unroll
    for (int j = 0; j < 16; ++j)
        u16[j] = f2bfu(tile[c16l * 16 + j][n16l * 16 + n_loc]);
    unsigned short* dst = xp + (((size_t)(b * 1024 + (n0 >> 4) + n16l)) * 16
                                + (c0 >> 4) + c16l) * 256 + n_loc * 16;
    *reinterpret_cast<uint4*>(dst)     = *reinterpret_cast<const uint4*>(u16);
    *reinterpret_cast<uint4*>(dst + 8) = *reinterpret_cast<const uint4*>(u16 + 8);
}

// ---------------------------------------------------------------------------
// K0b: all weight frag tiles (unchanged).
// ---------------------------------------------------------------------------
__global__ __launch_bounds__(256) void wconv3(const float* __restrict__ w_qkv,
                                              const float* __restrict__ w_out,
                                              unsigned short* __restrict__ WkF,
                                              unsigned short* __restrict__ WvF,
                                              unsigned short* __restrict__ WqTF,
                                              unsigned short* __restrict__ WoF)
{
    const int t = threadIdx.x, lane = t & 63, wid = t >> 6;
    const int tile = blockIdx.x * 4 + wid;
    unsigned short u8[8];
    unsigned short* dst;
    if (tile < 256) {                       // WkF [h][d16 8][c32 8]
        const int h = tile >> 6, d16 = (tile >> 3) & 7, c32 = tile & 7;
        const float* src = w_qkv + (size_t)(512 + h * 128 + d16 * 16 + (lane & 15)) * CIN
                         + c32 * 32 + (lane >> 4) * 8;
#pragma unroll
        for (int j = 0; j < 8; ++j) u8[j] = f2bfu(src[j]);
        dst = WkF + (size_t)tile * 512 + lane * 8;
    } else if (tile < 512) {                // WvF [h][e16 8][c32 8]
        const int t2 = tile - 256;
        const int h = t2 >> 6, e16 = (t2 >> 3) & 7, c32 = t2 & 7;
        const float* src = w_qkv + (size_t)(1024 + h * 128 + e16 * 16 + (lane & 15)) * CIN
                         + c32 * 32 + (lane >> 4) * 8;
#pragma unroll
        for (int j = 0; j < 8; ++j) u8[j] = f2bfu(src[j]);
        dst = WvF + (size_t)t2 * 512 + lane * 8;
    } else if (tile < 768) {                // WqTF [h][c16 16][d32 4]
        const int t2 = tile - 512;
        const int h = t2 >> 6, c16 = (t2 >> 2) & 15, d32 = t2 & 3;
#pragma unroll
        for (int j = 0; j < 8; ++j)
            u8[j] = f2bfu(w_qkv[(size_t)(h * 128 + d32 * 32 + (lane >> 4) * 8 + j) * CIN
                                + c16 * 16 + (lane & 15)]);
        dst = WqTF + (size_t)t2 * 512 + lane * 8;
    } else {                                // WoF [o16 16][m32 16]
        const int t2 = tile - 768;
        const int o16 = t2 >> 4, m32 = t2 & 15;
        const float* src = w_out + (size_t)(o16 * 16 + (lane & 15)) * HID
                         + m32 * 32 + (lane >> 4) * 8;
#pragma unroll
        for (int j = 0; j < 8; ++j) u8[j] = f2bfu(src[j]);
        dst = WoF + (size_t)t2 * 512 + lane * 8;
    }
    *reinterpret_cast<uint4*>(dst) = *reinterpret_cast<const uint4*>(u8);
}

// ---------------------------------------------------------------------------
// K1: fused kg — R6 phase structure, ONE x buffer in LDS (plain tiles):
//   GEMM1-B via per-lane ds_read_b128; GEMM2-B via ds_read_b64_tr_b16 pairs
//   (per-lane addr = blockbase + 8*(lane&15); lane i receives bytes
//    blockbase + 32j + 2i = x[n=kn*32+q*8+j][c=c16*16+i]).
//   LDS 80 KB -> 2 blocks/CU.  Epilogue: plain stores to Gp (no atomics).
// launch: 256 blocks x 512 threads.
// ---------------------------------------------------------------------------
__global__ __launch_bounds__(512, 4) void kg_fused7(const unsigned short* __restrict__ xp,
                                                    const unsigned short* __restrict__ WkF,
                                                    float* __restrict__ Gp,
                                                    float* __restrict__ S)
{
    __shared__ unsigned short sX[2][64 * 256];   // 2 x 32 KB: [n16l 4][c16 16] plain tiles
    __shared__ unsigned short sP[16 * 512];      // 16 KB: 8 d16 x 2 n32 frag tiles

    // XCD co-location remap (neutral-proven, kept)
    const int wgid = blockIdx.x;
    const int xcd  = wgid & 7;
    const int k_   = wgid >> 3;
    const int h    = k_ & 3;
    const int g_   = xcd + 8 * (k_ >> 2);
    const int ns   = g_ & 15;
    const int b    = g_ >> 4;
    const int bh   = b * 4 + h;

    const int t = threadIdx.x, lane = t & 63, wid = t >> 6;
    const int wm = wid >> 1, wn = wid & 1;    // GEMM1: 4x2 waves -> 32d x 32n each
    const int wd = wid >> 2, wcq = wid & 3;   // GEMM2: 2x4 waves -> 64d x 64c each
    const int cl = lane & 15, q = lane >> 4, r0q = q * 4;
    const int boff  = cl * 16 + (q & 1) * 8 + (q >> 1) * 256;   // GEMM1-B us offset
    const unsigned troff = (unsigned)((q >> 1) * 8192 + (q & 1) * 256 + cl * 8); // GEMM2 tr bytes

    // persistent Wk fragments: 64 VGPR
    bf16x8 aW[2][8];
#pragma unroll
    for (int fi = 0; fi < 2; ++fi)
#pragma unroll
        for (int ks = 0; ks < 8; ++ks)
            aW[fi][ks] = *reinterpret_cast<const bf16x8*>(
                WkF + ((size_t)(h * 64 + (wm * 2 + fi) * 8 + ks)) * 512 + lane * 8);

    f32x4 accG[4][4] = {};
    float Sacc[8] = {};

    const unsigned short* xpb = xp + ((size_t)(b * 1024 + ns * 64) * 16) * 256;

#define STAGE(nt_, buf_)                                                        \
    {                                                                           \
        const unsigned short* src_ = xpb + (size_t)(nt_) * 16384;               \
        _Pragma("unroll")                                                       \
        for (int p = 0; p < 4; ++p)                                             \
            glds16(src_ + ((size_t)p * 512 + t) * 8,                            \
                   &sX[buf_][((size_t)p * 512 + wid * 64) * 8]);                \
    }

    STAGE(0, 0);
    __syncthreads();

    int cur = 0;
    for (int nt = 0; nt < 16; ++nt) {
        if (nt < 15) STAGE(nt + 1, cur ^ 1);

        // ---- GEMM1: logits 32d x 32n per wave, K=256 ----
        f32x4 acc1[2][2] = {};
#pragma unroll
        for (int ks = 0; ks < 8; ++ks) {
            bf16x8 bb[2];
#pragma unroll
            for (int fj = 0; fj < 2; ++fj)
                bb[fj] = *reinterpret_cast<const bf16x8*>(
                    &sX[cur][((wn * 2 + fj) * 16 + 2 * ks) * 256 + boff]);
#pragma unroll
            for (int fi = 0; fi < 2; ++fi)
#pragma unroll
                for (int fj = 0; fj < 2; ++fj)
                    acc1[fi][fj] = __builtin_amdgcn_mfma_f32_16x16x32_bf16(
                        aW[fi][ks], bb[fj], acc1[fi][fj], 0, 0, 0);
        }

        // ---- exp -> sP (frag-tiled) + rowsum ----
#pragma unroll
        for (int fi = 0; fi < 2; ++fi)
#pragma unroll
            for (int r = 0; r < 4; ++r) {
                float rs = 0.f;
#pragma unroll
                for (int fj = 0; fj < 2; ++fj) {
                    const float v = __expf(acc1[fi][fj][r]);
                    rs += v;
                    const int us = ((r0q + r) + 16 * (fj * 2 + (cl >> 3))) * 8 + (cl & 7);
                    sP[((wm * 2 + fi) * 2 + wn) * 512 + us] = f2bfu(v);
                }
                Sacc[fi * 4 + r] += rs;
            }
        __syncthreads();   // sP ready; nt+1 stages still in flight (vmcnt)

        // ---- GEMM2: G[64d x 64c] per wave += P * x (contract 64 n) ----
        {
            const unsigned sx_base = lds_off(&sX[cur][0]);
#pragma unroll
            for (int kn = 0; kn < 2; ++kn) {
                u32x2 lo[4], hi[4];
#pragma unroll
                for (int fj = 0; fj < 4; ++fj) {
                    const int cc = wcq * 4 + fj;
                    const unsigned a = sx_base + (unsigned)((kn * 32 + cc) * 512) + troff;
                    asm volatile("ds_read_b64_tr_b16 %0, %2\n\t"
                                 "ds_read_b64_tr_b16 %1, %2 offset:128"
                                 : "=&v"(lo[fj]), "=&v"(hi[fj])
                                 : "v"(a));
                }
                asm volatile("s_waitcnt lgkmcnt(0)" ::: "memory");
                __builtin_amdgcn_sched_barrier(0);

                bf16x8 pa[4];
#pragma unroll
                for (int fi = 0; fi < 4; ++fi)
                    pa[fi] = *reinterpret_cast<const bf16x8*>(
                        &sP[((wd * 4 + fi) * 2 + kn) * 512 + lane * 8]);
#pragma unroll
                for (int fj = 0; fj < 4; ++fj) {
                    union { bf16x8 v; u32x2 h2[2]; } fb;
                    fb.h2[0] = lo[fj];
                    fb.h2[1] = hi[fj];
#pragma unroll
                    for (int fi = 0; fi < 4; ++fi)
                        accG[fi][fj] = __builtin_amdgcn_mfma_f32_16x16x32_bf16(
                            pa[fi], fb.v, accG[fi][fj], 0, 0, 0);
                }
            }
        }
        __syncthreads();   // drains nt+1 stages + WAR on sX bufs
        cur ^= 1;
    }
#undef STAGE

    // ---- S rowsums ----
#pragma unroll
    for (int i = 0; i < 8; ++i) {
        float v = Sacc[i];
        v += __shfl_xor(v, 1); v += __shfl_xor(v, 2);
        v += __shfl_xor(v, 4); v += __shfl_xor(v, 8);
        if (cl == 0) {
            const int d = wm * 32 + (i >> 2) * 16 + r0q + (i & 3);
            atomicAdd(&S[bh * 128 + d], v);
        }
    }

    // ---- G partial write (plain coalesced stores) ----
    float* gp = Gp + (size_t)(ns * 16 + bh) * (128 * 256);
#pragma unroll
    for (int fi = 0; fi < 4; ++fi)
#pragma unroll
        for (int fj = 0; fj < 4; ++fj)
#pragma unroll
            for (int r = 0; r < 4; ++r)
                gp[(size_t)(wd * 64 + fi * 16 + r0q + r) * 256 + wcq * 64 + fj * 16 + cl]
                    = accG[fi][fj][r];
}

// K2: G[bh][d][c] = sum over 16 splits
__global__ __launch_bounds__(256) void g_reduce2(const float* __restrict__ Gp,
                                                 float* __restrict__ G)
{
    const int idx = blockIdx.x * 256 + threadIdx.x;
    const int bh = idx >> 15, dc = idx & 32767;
    float s = 0.f;
#pragma unroll
    for (int k = 0; k < 16; ++k)
        s += Gp[((size_t)k * 16 + bh) * 32768 + dc];
    G[idx] = s;
}

// ---------------------------------------------------------------------------
// C1: per bh: ctx = (G/S) x Wv^T, then Abar = ctx^T x Wq -> AbarF frag tiles.
// ---------------------------------------------------------------------------
__global__ __launch_bounds__(256) void c1_kernel(const float* __restrict__ G,
                                                 const float* __restrict__ S,
                                                 const unsigned short* __restrict__ WvF,
                                                 const unsigned short* __restrict__ WqTF,
                                                 unsigned short* __restrict__ AbarF)
{
    __shared__ unsigned short sCtx[32 * 512];
    const int t = threadIdx.x, lane = t & 63, wid = t >> 6;
    const int bh = blockIdx.x, b = bh >> 2, h = bh & 3;
    const int cl = lane & 15, r0q = (lane >> 4) * 4;
    const int wr = wid >> 1, wc = wid & 1;
    const float* Gb = G + (size_t)bh * 32768;

    float invs[4];
#pragma unroll
    for (int fi = 0; fi < 4; ++fi)
        invs[fi] = 1.0f / S[bh * 128 + wr * 64 + fi * 16 + cl];

    f32x4 acc[4][4] = {};
#pragma unroll
    for (int ks = 0; ks < 8; ++ks) {
        bf16x8 a[4], bb[4];
#pragma unroll
        for (int fi = 0; fi < 4; ++fi) {
            const float* gp = Gb + (size_t)(wr * 64 + fi * 16 + cl) * 256
                            + ks * 32 + (lane >> 4) * 8;
            const float4 v0 = *reinterpret_cast<const float4*>(gp);
            const float4 v1 = *reinterpret_cast<const float4*>(gp + 4);
            unsigned short u8[8] = {
                f2bfu(v0.x * invs[fi]), f2bfu(v0.y * invs[fi]),
                f2bfu(v0.z * invs[fi]), f2bfu(v0.w * invs[fi]),
                f2bfu(v1.x * invs[fi]), f2bfu(v1.y * invs[fi]),
                f2bfu(v1.z * invs[fi]), f2bfu(v1.w * invs[fi]) };
            a[fi] = *reinterpret_cast<const bf16x8*>(u8);
        }
#pragma unroll
        for (int fj = 0; fj < 4; ++fj)
            bb[fj] = *reinterpret_cast<const bf16x8*>(
                WvF + ((size_t)(h * 8 + wc * 4 + fj) * 8 + ks) * 512 + lane * 8);
#pragma unroll
        for (int fi = 0; fi < 4; ++fi)
#pragma unroll
            for (int fj = 0; fj < 4; ++fj)
                acc[fi][fj] = __builtin_amdgcn_mfma_f32_16x16x32_bf16(
                    a[fi], bb[fj], acc[fi][fj], 0, 0, 0);
    }

#pragma unroll
    for (int fi = 0; fi < 4; ++fi)
#pragma unroll
        for (int fj = 0; fj < 4; ++fj)
#pragma unroll
            for (int r = 0; r < 4; ++r) {
                const int us = (cl + 16 * ((fi & 1) * 2 + ((r0q + r) >> 3))) * 8 + ((r0q + r) & 7);
                sCtx[((wc * 4 + fj) * 4 + wr * 2 + (fi >> 1)) * 512 + us] = f2bfu(acc[fi][fj][r]);
            }
    __syncthreads();

    const int we = wid >> 1, wcq = wid & 1;
    f32x4 acc2[4][8] = {};
#pragma unroll
    for (int ks = 0; ks < 4; ++ks) {
        bf16x8 a2[4], b2[8];
#pragma unroll
        for (int fi = 0; fi < 4; ++fi)
            a2[fi] = *reinterpret_cast<const bf16x8*>(
                &sCtx[((we * 4 + fi) * 4 + ks) * 512 + lane * 8]);
#pragma unroll
        for (int fj = 0; fj < 8; ++fj)
            b2[fj] = *reinterpret_cast<const bf16x8*>(
                WqTF + ((size_t)(h * 16 + wcq * 8 + fj) * 4 + ks) * 512 + lane * 8);
#pragma unroll
        for (int fi = 0; fi < 4; ++fi)
#pragma unroll
            for (int fj = 0; fj < 8; ++fj)
                acc2[fi][fj] = __builtin_amdgcn_mfma_f32_16x16x32_bf16(
                    a2[fi], b2[fj], acc2[fi][fj], 0, 0, 0);
    }

#pragma unroll
    for (int fi = 0; fi < 4; ++fi)
#pragma unroll
        for (int fj = 0; fj < 8; ++fj)
#pragma unroll
            for (int r = 0; r < 4; ++r) {
                const int c16 = wcq * 8 + fj;
                const int m32 = h * 4 + we * 2 + (fi >> 1);
                const int us  = (cl + 16 * ((fi & 1) * 2 + ((r0q + r) >> 3))) * 8 + ((r0q + r) & 7);
                AbarF[((size_t)(b * 16 + c16) * 16 + m32) * 512 + us] = f2bfu(acc2[fi][fj][r]);
            }
}

// ---------------------------------------------------------------------------
// C2: F[b][256o x 64c] = Wo x Abar (K=512), no LDS.
// ---------------------------------------------------------------------------
__global__ __launch_bounds__(256) void c2_kernel(const unsigned short* __restrict__ WoF,
                                                 const unsigned short* __restrict__ AbarF,
                                                 unsigned short* __restrict__ F2)
{
    const int t = threadIdx.x, lane = t & 63, wid = t >> 6;
    const int csp = blockIdx.x, b = blockIdx.y;
    const int cl = lane & 15, r0q = (lane >> 4) * 4;

    f32x4 acc[4][4] = {};
#pragma unroll
    for (int ks = 0; ks < 16; ++ks) {
        bf16x8 a[4], bb[4];
#pragma unroll
        for (int fi = 0; fi < 4; ++fi)
            a[fi] = *reinterpret_cast<const bf16x8*>(
                WoF + ((size_t)(wid * 4 + fi) * 16 + ks) * 512 + lane * 8);
#pragma unroll
        for (int fj = 0; fj < 4; ++fj)
            bb[fj] = *reinterpret_cast<const bf16x8*>(
                AbarF + ((size_t)(b * 16 + csp * 4 + fj) * 16 + ks) * 512 + lane * 8);
#pragma unroll
        for (int fi = 0; fi < 4; ++fi)
#pragma unroll
            for (int fj = 0; fj < 4; ++fj)
                acc[fi][fj] = __builtin_amdgcn_mfma_f32_16x16x32_bf16(
                    a[fi], bb[fj], acc[fi][fj], 0, 0, 0);
    }

#pragma unroll
    for (int fi = 0; fi < 4; ++fi)
#pragma unroll
        for (int fj = 0; fj < 4; ++fj)
#pragma unroll
            for (int r = 0; r < 4; ++r) {
                const int o16 = wid * 4 + fi;
                const int c32 = csp * 2 + (fj >> 1);
                const int us  = ((r0q + r) + 16 * ((fj & 1) * 2 + (cl >> 3))) * 8 + (cl & 7);
                F2[((size_t)(b * 16 + o16) * 8 + c32) * 512 + us] = f2bfu(acc[fi][fj][r]);
            }
}

// ---------------------------------------------------------------------------
// K6: out GEMM.  Stage whole xp n-panel (64 KB = 128 tiles) once; F2 from L2.
// grid (128, 2, 4), block 256 (2x2 waves of 64o x 64n)
// ---------------------------------------------------------------------------
__global__ __launch_bounds__(256, 2) void out_gemm4(const unsigned short* __restrict__ xp,
                                                    const unsigned short* __restrict__ F2,
                                                    const float* __restrict__ b_out,
                                                    float* __restrict__ out)
{
    __shared__ unsigned short sXT[128 * 256];   // 64 KB: [8 n16][16 c16] plain tiles
    const int t = threadIdx.x, lane = t & 63, wid = t >> 6;
    const int n0 = blockIdx.x * 128, m0 = blockIdx.y * 128, b = blockIdx.z;
    const int wr = wid >> 1, wc = wid & 1;
    const int cl = lane & 15, q = lane >> 4;
    const int boff = cl * 16 + (q & 1) * 8 + (q >> 1) * 256;

    const unsigned short* src = xp + ((size_t)(b * 1024 + (n0 >> 4)) * 16) * 256;
#pragma unroll
    for (int p = 0; p < 16; ++p)     // FIXED: 16 x 256 threads x 16B = full 64 KB
        glds16(src + ((size_t)p * 256 + t) * 8, &sXT[((size_t)p * 256 + wid * 64) * 8]);
    __syncthreads();

    f32x4 acc[4][4] = {};
#pragma unroll
    for (int ks = 0; ks < 8; ++ks) {
        bf16x8 a[4], bb[4];
#pragma unroll
        for (int fi = 0; fi < 4; ++fi)
            a[fi] = *reinterpret_cast<const bf16x8*>(
                F2 + (((size_t)b * 16 + (m0 >> 4) + wr * 4 + fi) * 8 + ks) * 512 + lane * 8);
#pragma unroll
        for (int fj = 0; fj < 4; ++fj)
            bb[fj] = *reinterpret_cast<const bf16x8*>(
                &sXT[((wc * 4 + fj) * 16 + 2 * ks) * 256 + boff]);
#pragma unroll
        for (int fi = 0; fi < 4; ++fi)
#pragma unroll
            for (int fj = 0; fj < 4; ++fj)
                acc[fi][fj] = __builtin_amdgcn_mfma_f32_16x16x32_bf16(
                    a[fi], bb[fj], acc[fi][fj], 0, 0, 0);
    }

    const int r0q = q * 4;
#pragma unroll
    for (int fi = 0; fi < 4; ++fi)
#pragma unroll
        for (int r = 0; r < 4; ++r) {
            const int o = m0 + wr * 64 + fi * 16 + r0q + r;
            const float bias = b_out[o];
#pragma unroll
            for (int fj = 0; fj < 4; ++fj)
                out[((size_t)b * CIN + o) * NPIX + n0 + wc * 64 + fj * 16 + cl] =
                    acc[fi][fj][r] + bias;
        }
}

// ---------------------------------------------------------------------------
extern "C" void kernel_launch(void* const* d_in, const int* in_sizes, int n_in,
                              void* d_out, int out_size, void* d_ws, size_t ws_size,
                              hipStream_t stream)
{
    const float* x     = (const float*)d_in[0];
    const float* w_qkv = (const float*)d_in[1];
    const float* w_out = (const float*)d_in[2];
    const float* b_out = (const float*)d_in[3];
    float* out = (float*)d_out;

    char* ws = (char*)d_ws;
    unsigned short* xp    = (unsigned short*)ws;                           // 32 MB
    unsigned short* WkF   = (unsigned short*)(ws + (64ull << 20));         // 256 KB
    unsigned short* WvF   = (unsigned short*)(ws + (64ull << 20) + (256u << 10));
    unsigned short* WqTF  = (unsigned short*)(ws + (64ull << 20) + (512u << 10));
    unsigned short* WoF   = (unsigned short*)(ws + (64ull << 20) + (768u << 10));
    float*          S     = (float*)(ws + (65ull << 20));                  // 8 KB
    float*          G     = (float*)(ws + (66ull << 20));                  // 2 MB
    unsigned short* AbarF = (unsigned short*)(ws + (68ull << 20));         // 256 KB
    unsigned short* F2    = (unsigned short*)(ws + (69ull << 20));         // 512 KB
    float*          Gp    = (float*)(ws + (72ull << 20));                  // 33.5 MB

    hipMemsetAsync(S, 0, 2048 * sizeof(float), stream);
    xp_convert<<<dim3(NPIX / 64, CIN / 64, NB), 256, 0, stream>>>(x, xp);
    wconv3<<<256, 256, 0, stream>>>(w_qkv, w_out, WkF, WvF, WqTF, WoF);
    kg_fused7<<<256, 512, 0, stream>>>(xp, WkF, Gp, S);
    g_reduce2<<<2048, 256, 0, stream>>>(Gp, G);
    c1_kernel<<<16, 256, 0, stream>>>(G, S, WvF, WqTF, AbarF);
    c2_kernel<<<dim3(4, NB), 256, 0, stream>>>(WoF, AbarF, F2);
    out_gemm4<<<dim3(NPIX / 128, CIN / 128, NB), 256, 0, stream>>>(xp, F2, b_out, out);
}

// Round 13
// 127.452 us; speedup vs baseline: 1.5992x; 1.5992x over previous
//
#include <hip/hip_runtime.h>
#include <hip/hip_bf16.h>

#define HEADS 4
#define DH    128
#define CIN   256
#define NPIX  16384
#define NB    4
#define HID   512

typedef __attribute__((ext_vector_type(8))) short bf16x8;
typedef __attribute__((ext_vector_type(4))) float f32x4;
typedef __attribute__((ext_vector_type(2))) unsigned u32x2;

__device__ __forceinline__ unsigned short f2bfu(float f) {
    union { __hip_bfloat16 h; unsigned short u; } cv;
    cv.h = __float2bfloat16(f);
    return cv.u;
}

// ---- async global->LDS, 16B per lane --------------------------------------
typedef const __attribute__((address_space(1))) unsigned char* gas_t;
typedef __attribute__((address_space(3))) unsigned char* las_t;
__device__ __forceinline__ void glds16(const void* g, void* s) {
    __builtin_amdgcn_global_load_lds((gas_t)g, (las_t)s, 16, 0, 0);
}
__device__ __forceinline__ unsigned lds_off(const void* p) {
    return (unsigned)(size_t)(las_t)p;
}

// Frag-tile (weights/P/F): 16(row) x 32(k) bf16 = 512 ushorts, lane-major:
// element (row r, k) at us = (r + 16*(k>>3))*8 + (k&7).
// Plain tile (x): 16c x 16n, element (c,n) at us = (n&15)*16 + (c&15).

// ---------------------------------------------------------------------------
// K0a: x[b][c][n] fp32 -> xp plain tiles [b][n16 1024][c16 16][256]
// grid (256, 4, 4), block 256
// ---------------------------------------------------------------------------
__global__ __launch_bounds__(256) void xp_convert(const float* __restrict__ x,
                                                  unsigned short* __restrict__ xp)
{
    __shared__ float tile[64][67];
    const int b = blockIdx.z, c0 = blockIdx.y * 64, n0 = blockIdx.x * 64;
    const int t = threadIdx.x;
    const float* xb = x + ((size_t)b * CIN + c0) * NPIX + n0;
#pragma unroll
    for (int p = 0; p < 4; ++p) {
        const int c = p * 16 + (t >> 4);
        const int n = (t & 15) * 4;
        float4 v = *reinterpret_cast<const float4*>(xb + (size_t)c * NPIX + n);
        tile[c][n + 0] = v.x; tile[c][n + 1] = v.y;
        tile[c][n + 2] = v.z; tile[c][n + 3] = v.w;
    }
    __syncthreads();
    // each thread writes one 16-c row of one tile (32B)
    const int n16l = t >> 6, c16l = (t >> 4) & 3, n_loc = t & 15;
    unsigned short u16[16];
#pragma unroll
    for (int j = 0; j < 16; ++j)
        u16[j] = f2bfu(tile[c16l * 16 + j][n16l * 16 + n_loc]);
    unsigned short* dst = xp + (((size_t)(b * 1024 + (n0 >> 4) + n16l)) * 16
                                + (c0 >> 4) + c16l) * 256 + n_loc * 16;
    *reinterpret_cast<uint4*>(dst)     = *reinterpret_cast<const uint4*>(u16);
    *reinterpret_cast<uint4*>(dst + 8) = *reinterpret_cast<const uint4*>(u16 + 8);
}

// ---------------------------------------------------------------------------
// K0b: all weight frag tiles (unchanged).
// ---------------------------------------------------------------------------
__global__ __launch_bounds__(256) void wconv3(const float* __restrict__ w_qkv,
                                              const float* __restrict__ w_out,
                                              unsigned short* __restrict__ WkF,
                                              unsigned short* __restrict__ WvF,
                                              unsigned short* __restrict__ WqTF,
                                              unsigned short* __restrict__ WoF)
{
    const int t = threadIdx.x, lane = t & 63, wid = t >> 6;
    const int tile = blockIdx.x * 4 + wid;
    unsigned short u8[8];
    unsigned short* dst;
    if (tile < 256) {                       // WkF [h][d16 8][c32 8]
        const int h = tile >> 6, d16 = (tile >> 3) & 7, c32 = tile & 7;
        const float* src = w_qkv + (size_t)(512 + h * 128 + d16 * 16 + (lane & 15)) * CIN
                         + c32 * 32 + (lane >> 4) * 8;
#pragma unroll
        for (int j = 0; j < 8; ++j) u8[j] = f2bfu(src[j]);
        dst = WkF + (size_t)tile * 512 + lane * 8;
    } else if (tile < 512) {                // WvF [h][e16 8][c32 8]
        const int t2 = tile - 256;
        const int h = t2 >> 6, e16 = (t2 >> 3) & 7, c32 = t2 & 7;
        const float* src = w_qkv + (size_t)(1024 + h * 128 + e16 * 16 + (lane & 15)) * CIN
                         + c32 * 32 + (lane >> 4) * 8;
#pragma unroll
        for (int j = 0; j < 8; ++j) u8[j] = f2bfu(src[j]);
        dst = WvF + (size_t)t2 * 512 + lane * 8;
    } else if (tile < 768) {                // WqTF [h][c16 16][d32 4]
        const int t2 = tile - 512;
        const int h = t2 >> 6, c16 = (t2 >> 2) & 15, d32 = t2 & 3;
#pragma unroll
        for (int j = 0; j < 8; ++j)
            u8[j] = f2bfu(w_qkv[(size_t)(h * 128 + d32 * 32 + (lane >> 4) * 8 + j) * CIN
                                + c16 * 16 + (lane & 15)]);
        dst = WqTF + (size_t)t2 * 512 + lane * 8;
    } else {                                // WoF [o16 16][m32 16]
        const int t2 = tile - 768;
        const int o16 = t2 >> 4, m32 = t2 & 15;
        const float* src = w_out + (size_t)(o16 * 16 + (lane & 15)) * HID
                         + m32 * 32 + (lane >> 4) * 8;
#pragma unroll
        for (int j = 0; j < 8; ++j) u8[j] = f2bfu(src[j]);
        dst = WoF + (size_t)t2 * 512 + lane * 8;
    }
    *reinterpret_cast<uint4*>(dst) = *reinterpret_cast<const uint4*>(u8);
}

// ---------------------------------------------------------------------------
// K1: fused kg — R6 phase structure, ONE x buffer in LDS (plain tiles):
//   GEMM1-B via per-lane ds_read_b128; GEMM2-B via ds_read_b64_tr_b16 pairs.
//   LDS 80 KB.  launch_bounds(512,2): VGPR cap 256 -> NO SPILL (the (512,4)
//   variant capped unified regs at 128 -> ~40 spilled VGPRs -> 130 MB scratch
//   traffic, R12's regression).  Epilogue: plain stores to Gp.
// launch: 256 blocks x 512 threads.
// ---------------------------------------------------------------------------
__global__ __launch_bounds__(512, 2) void kg_fused7(const unsigned short* __restrict__ xp,
                                                    const unsigned short* __restrict__ WkF,
                                                    float* __restrict__ Gp,
                                                    float* __restrict__ S)
{
    __shared__ unsigned short sX[2][64 * 256];   // 2 x 32 KB: [n16l 4][c16 16] plain tiles
    __shared__ unsigned short sP[16 * 512];      // 16 KB: 8 d16 x 2 n32 frag tiles

    // XCD co-location remap (neutral-proven, kept)
    const int wgid = blockIdx.x;
    const int xcd  = wgid & 7;
    const int k_   = wgid >> 3;
    const int h    = k_ & 3;
    const int g_   = xcd + 8 * (k_ >> 2);
    const int ns   = g_ & 15;
    const int b    = g_ >> 4;
    const int bh   = b * 4 + h;

    const int t = threadIdx.x, lane = t & 63, wid = t >> 6;
    const int wm = wid >> 1, wn = wid & 1;    // GEMM1: 4x2 waves -> 32d x 32n each
    const int wd = wid >> 2, wcq = wid & 3;   // GEMM2: 2x4 waves -> 64d x 64c each
    const int cl = lane & 15, q = lane >> 4, r0q = q * 4;
    const int boff  = cl * 16 + (q & 1) * 8 + (q >> 1) * 256;   // GEMM1-B us offset
    const unsigned troff = (unsigned)((q >> 1) * 8192 + (q & 1) * 256 + cl * 8); // GEMM2 tr bytes

    // persistent Wk fragments: 64 VGPR
    bf16x8 aW[2][8];
#pragma unroll
    for (int fi = 0; fi < 2; ++fi)
#pragma unroll
        for (int ks = 0; ks < 8; ++ks)
            aW[fi][ks] = *reinterpret_cast<const bf16x8*>(
                WkF + ((size_t)(h * 64 + (wm * 2 + fi) * 8 + ks)) * 512 + lane * 8);

    f32x4 accG[4][4] = {};
    float Sacc[8] = {};

    const unsigned short* xpb = xp + ((size_t)(b * 1024 + ns * 64) * 16) * 256;

#define STAGE(nt_, buf_)                                                        \
    {                                                                           \
        const unsigned short* src_ = xpb + (size_t)(nt_) * 16384;               \
        _Pragma("unroll")                                                       \
        for (int p = 0; p < 4; ++p)                                             \
            glds16(src_ + ((size_t)p * 512 + t) * 8,                            \
                   &sX[buf_][((size_t)p * 512 + wid * 64) * 8]);                \
    }

    STAGE(0, 0);
    __syncthreads();

    int cur = 0;
    for (int nt = 0; nt < 16; ++nt) {
        if (nt < 15) STAGE(nt + 1, cur ^ 1);

        // ---- GEMM1: logits 32d x 32n per wave, K=256 ----
        f32x4 acc1[2][2] = {};
#pragma unroll
        for (int ks = 0; ks < 8; ++ks) {
            bf16x8 bb[2];
#pragma unroll
            for (int fj = 0; fj < 2; ++fj)
                bb[fj] = *reinterpret_cast<const bf16x8*>(
                    &sX[cur][((wn * 2 + fj) * 16 + 2 * ks) * 256 + boff]);
#pragma unroll
            for (int fi = 0; fi < 2; ++fi)
#pragma unroll
                for (int fj = 0; fj < 2; ++fj)
                    acc1[fi][fj] = __builtin_amdgcn_mfma_f32_16x16x32_bf16(
                        aW[fi][ks], bb[fj], acc1[fi][fj], 0, 0, 0);
        }

        // ---- exp -> sP (frag-tiled) + rowsum ----
#pragma unroll
        for (int fi = 0; fi < 2; ++fi)
#pragma unroll
            for (int r = 0; r < 4; ++r) {
                float rs = 0.f;
#pragma unroll
                for (int fj = 0; fj < 2; ++fj) {
                    const float v = __expf(acc1[fi][fj][r]);
                    rs += v;
                    const int us = ((r0q + r) + 16 * (fj * 2 + (cl >> 3))) * 8 + (cl & 7);
                    sP[((wm * 2 + fi) * 2 + wn) * 512 + us] = f2bfu(v);
                }
                Sacc[fi * 4 + r] += rs;
            }
        __syncthreads();   // sP ready; nt+1 stages still in flight (vmcnt)

        // ---- GEMM2: G[64d x 64c] per wave += P * x (contract 64 n) ----
        {
            const unsigned sx_base = lds_off(&sX[cur][0]);
#pragma unroll
            for (int kn = 0; kn < 2; ++kn) {
                u32x2 lo[4], hi[4];
#pragma unroll
                for (int fj = 0; fj < 4; ++fj) {
                    const int cc = wcq * 4 + fj;
                    const unsigned a = sx_base + (unsigned)((kn * 32 + cc) * 512) + troff;
                    asm volatile("ds_read_b64_tr_b16 %0, %2\n\t"
                                 "ds_read_b64_tr_b16 %1, %2 offset:128"
                                 : "=&v"(lo[fj]), "=&v"(hi[fj])
                                 : "v"(a));
                }
                asm volatile("s_waitcnt lgkmcnt(0)" ::: "memory");
                __builtin_amdgcn_sched_barrier(0);

                bf16x8 pa[4];
#pragma unroll
                for (int fi = 0; fi < 4; ++fi)
                    pa[fi] = *reinterpret_cast<const bf16x8*>(
                        &sP[((wd * 4 + fi) * 2 + kn) * 512 + lane * 8]);
#pragma unroll
                for (int fj = 0; fj < 4; ++fj) {
                    union { bf16x8 v; u32x2 h2[2]; } fb;
                    fb.h2[0] = lo[fj];
                    fb.h2[1] = hi[fj];
#pragma unroll
                    for (int fi = 0; fi < 4; ++fi)
                        accG[fi][fj] = __builtin_amdgcn_mfma_f32_16x16x32_bf16(
                            pa[fi], fb.v, accG[fi][fj], 0, 0, 0);
                }
            }
        }
        __syncthreads();   // drains nt+1 stages + WAR on sX bufs
        cur ^= 1;
    }
#undef STAGE

    // ---- S rowsums ----
#pragma unroll
    for (int i = 0; i < 8; ++i) {
        float v = Sacc[i];
        v += __shfl_xor(v, 1); v += __shfl_xor(v, 2);
        v += __shfl_xor(v, 4); v += __shfl_xor(v, 8);
        if (cl == 0) {
            const int d = wm * 32 + (i >> 2) * 16 + r0q + (i & 3);
            atomicAdd(&S[bh * 128 + d], v);
        }
    }

    // ---- G partial write (plain coalesced stores) ----
    float* gp = Gp + (size_t)(ns * 16 + bh) * (128 * 256);
#pragma unroll
    for (int fi = 0; fi < 4; ++fi)
#pragma unroll
        for (int fj = 0; fj < 4; ++fj)
#pragma unroll
            for (int r = 0; r < 4; ++r)
                gp[(size_t)(wd * 64 + fi * 16 + r0q + r) * 256 + wcq * 64 + fj * 16 + cl]
                    = accG[fi][fj][r];
}

// K2: G[bh][d][c] = sum over 16 splits
__global__ __launch_bounds__(256) void g_reduce2(const float* __restrict__ Gp,
                                                 float* __restrict__ G)
{
    const int idx = blockIdx.x * 256 + threadIdx.x;
    const int bh = idx >> 15, dc = idx & 32767;
    float s = 0.f;
#pragma unroll
    for (int k = 0; k < 16; ++k)
        s += Gp[((size_t)k * 16 + bh) * 32768 + dc];
    G[idx] = s;
}

// ---------------------------------------------------------------------------
// C1: per bh: ctx = (G/S) x Wv^T, then Abar = ctx^T x Wq -> AbarF frag tiles.
// ---------------------------------------------------------------------------
__global__ __launch_bounds__(256) void c1_kernel(const float* __restrict__ G,
                                                 const float* __restrict__ S,
                                                 const unsigned short* __restrict__ WvF,
                                                 const unsigned short* __restrict__ WqTF,
                                                 unsigned short* __restrict__ AbarF)
{
    __shared__ unsigned short sCtx[32 * 512];
    const int t = threadIdx.x, lane = t & 63, wid = t >> 6;
    const int bh = blockIdx.x, b = bh >> 2, h = bh & 3;
    const int cl = lane & 15, r0q = (lane >> 4) * 4;
    const int wr = wid >> 1, wc = wid & 1;
    const float* Gb = G + (size_t)bh * 32768;

    float invs[4];
#pragma unroll
    for (int fi = 0; fi < 4; ++fi)
        invs[fi] = 1.0f / S[bh * 128 + wr * 64 + fi * 16 + cl];

    f32x4 acc[4][4] = {};
#pragma unroll
    for (int ks = 0; ks < 8; ++ks) {
        bf16x8 a[4], bb[4];
#pragma unroll
        for (int fi = 0; fi < 4; ++fi) {
            const float* gp = Gb + (size_t)(wr * 64 + fi * 16 + cl) * 256
                            + ks * 32 + (lane >> 4) * 8;
            const float4 v0 = *reinterpret_cast<const float4*>(gp);
            const float4 v1 = *reinterpret_cast<const float4*>(gp + 4);
            unsigned short u8[8] = {
                f2bfu(v0.x * invs[fi]), f2bfu(v0.y * invs[fi]),
                f2bfu(v0.z * invs[fi]), f2bfu(v0.w * invs[fi]),
                f2bfu(v1.x * invs[fi]), f2bfu(v1.y * invs[fi]),
                f2bfu(v1.z * invs[fi]), f2bfu(v1.w * invs[fi]) };
            a[fi] = *reinterpret_cast<const bf16x8*>(u8);
        }
#pragma unroll
        for (int fj = 0; fj < 4; ++fj)
            bb[fj] = *reinterpret_cast<const bf16x8*>(
                WvF + ((size_t)(h * 8 + wc * 4 + fj) * 8 + ks) * 512 + lane * 8);
#pragma unroll
        for (int fi = 0; fi < 4; ++fi)
#pragma unroll
            for (int fj = 0; fj < 4; ++fj)
                acc[fi][fj] = __builtin_amdgcn_mfma_f32_16x16x32_bf16(
                    a[fi], bb[fj], acc[fi][fj], 0, 0, 0);
    }

#pragma unroll
    for (int fi = 0; fi < 4; ++fi)
#pragma unroll
        for (int fj = 0; fj < 4; ++fj)
#pragma unroll
            for (int r = 0; r < 4; ++r) {
                const int us = (cl + 16 * ((fi & 1) * 2 + ((r0q + r) >> 3))) * 8 + ((r0q + r) & 7);
                sCtx[((wc * 4 + fj) * 4 + wr * 2 + (fi >> 1)) * 512 + us] = f2bfu(acc[fi][fj][r]);
            }
    __syncthreads();

    const int we = wid >> 1, wcq = wid & 1;
    f32x4 acc2[4][8] = {};
#pragma unroll
    for (int ks = 0; ks < 4; ++ks) {
        bf16x8 a2[4], b2[8];
#pragma unroll
        for (int fi = 0; fi < 4; ++fi)
            a2[fi] = *reinterpret_cast<const bf16x8*>(
                &sCtx[((we * 4 + fi) * 4 + ks) * 512 + lane * 8]);
#pragma unroll
        for (int fj = 0; fj < 8; ++fj)
            b2[fj] = *reinterpret_cast<const bf16x8*>(
                WqTF + ((size_t)(h * 16 + wcq * 8 + fj) * 4 + ks) * 512 + lane * 8);
#pragma unroll
        for (int fi = 0; fi < 4; ++fi)
#pragma unroll
            for (int fj = 0; fj < 8; ++fj)
                acc2[fi][fj] = __builtin_amdgcn_mfma_f32_16x16x32_bf16(
                    a2[fi], b2[fj], acc2[fi][fj], 0, 0, 0);
    }

#pragma unroll
    for (int fi = 0; fi < 4; ++fi)
#pragma unroll
        for (int fj = 0; fj < 8; ++fj)
#pragma unroll
            for (int r = 0; r < 4; ++r) {
                const int c16 = wcq * 8 + fj;
                const int m32 = h * 4 + we * 2 + (fi >> 1);
                const int us  = (cl + 16 * ((fi & 1) * 2 + ((r0q + r) >> 3))) * 8 + ((r0q + r) & 7);
                AbarF[((size_t)(b * 16 + c16) * 16 + m32) * 512 + us] = f2bfu(acc2[fi][fj][r]);
            }
}

// ---------------------------------------------------------------------------
// C2: F[b][256o x 64c] = Wo x Abar (K=512), no LDS.
// ---------------------------------------------------------------------------
__global__ __launch_bounds__(256) void c2_kernel(const unsigned short* __restrict__ WoF,
                                                 const unsigned short* __restrict__ AbarF,
                                                 unsigned short* __restrict__ F2)
{
    const int t = threadIdx.x, lane = t & 63, wid = t >> 6;
    const int csp = blockIdx.x, b = blockIdx.y;
    const int cl = lane & 15, r0q = (lane >> 4) * 4;

    f32x4 acc[4][4] = {};
#pragma unroll
    for (int ks = 0; ks < 16; ++ks) {
        bf16x8 a[4], bb[4];
#pragma unroll
        for (int fi = 0; fi < 4; ++fi)
            a[fi] = *reinterpret_cast<const bf16x8*>(
                WoF + ((size_t)(wid * 4 + fi) * 16 + ks) * 512 + lane * 8);
#pragma unroll
        for (int fj = 0; fj < 4; ++fj)
            bb[fj] = *reinterpret_cast<const bf16x8*>(
                AbarF + ((size_t)(b * 16 + csp * 4 + fj) * 16 + ks) * 512 + lane * 8);
#pragma unroll
        for (int fi = 0; fi < 4; ++fi)
#pragma unroll
            for (int fj = 0; fj < 4; ++fj)
                acc[fi][fj] = __builtin_amdgcn_mfma_f32_16x16x32_bf16(
                    a[fi], bb[fj], acc[fi][fj], 0, 0, 0);
    }

#pragma unroll
    for (int fi = 0; fi < 4; ++fi)
#pragma unroll
        for (int fj = 0; fj < 4; ++fj)
#pragma unroll
            for (int r = 0; r < 4; ++r) {
                const int o16 = wid * 4 + fi;
                const int c32 = csp * 2 + (fj >> 1);
                const int us  = ((r0q + r) + 16 * ((fj & 1) * 2 + (cl >> 3))) * 8 + (cl & 7);
                F2[((size_t)(b * 16 + o16) * 8 + c32) * 512 + us] = f2bfu(acc[fi][fj][r]);
            }
}

// ---------------------------------------------------------------------------
// K6: out GEMM.  Stage whole xp n-panel (64 KB = 128 tiles) once; F2 from L2.
// grid (128, 2, 4), block 256 (2x2 waves of 64o x 64n)
// ---------------------------------------------------------------------------
__global__ __launch_bounds__(256, 2) void out_gemm4(const unsigned short* __restrict__ xp,
                                                    const unsigned short* __restrict__ F2,
                                                    const float* __restrict__ b_out,
                                                    float* __restrict__ out)
{
    __shared__ unsigned short sXT[128 * 256];   // 64 KB: [8 n16][16 c16] plain tiles
    const int t = threadIdx.x, lane = t & 63, wid = t >> 6;
    const int n0 = blockIdx.x * 128, m0 = blockIdx.y * 128, b = blockIdx.z;
    const int wr = wid >> 1, wc = wid & 1;
    const int cl = lane & 15, q = lane >> 4;
    const int boff = cl * 16 + (q & 1) * 8 + (q >> 1) * 256;

    const unsigned short* src = xp + ((size_t)(b * 1024 + (n0 >> 4)) * 16) * 256;
#pragma unroll
    for (int p = 0; p < 16; ++p)
        glds16(src + ((size_t)p * 256 + t) * 8, &sXT[((size_t)p * 256 + wid * 64) * 8]);
    __syncthreads();

    f32x4 acc[4][4] = {};
#pragma unroll
    for (int ks = 0; ks < 8; ++ks) {
        bf16x8 a[4], bb[4];
#pragma unroll
        for (int fi = 0; fi < 4; ++fi)
            a[fi] = *reinterpret_cast<const bf16x8*>(
                F2 + (((size_t)b * 16 + (m0 >> 4) + wr * 4 + fi) * 8 + ks) * 512 + lane * 8);
#pragma unroll
        for (int fj = 0; fj < 4; ++fj)
            bb[fj] = *reinterpret_cast<const bf16x8*>(
                &sXT[((wc * 4 + fj) * 16 + 2 * ks) * 256 + boff]);
#pragma unroll
        for (int fi = 0; fi < 4; ++fi)
#pragma unroll
            for (int fj = 0; fj < 4; ++fj)
                acc[fi][fj] = __builtin_amdgcn_mfma_f32_16x16x32_bf16(
                    a[fi], bb[fj], acc[fi][fj], 0, 0, 0);
    }

    const int r0q = q * 4;
#pragma unroll
    for (int fi = 0; fi < 4; ++fi)
#pragma unroll
        for (int r = 0; r < 4; ++r) {
            const int o = m0 + wr * 64 + fi * 16 + r0q + r;
            const float bias = b_out[o];
#pragma unroll
            for (int fj = 0; fj < 4; ++fj)
                out[((size_t)b * CIN + o) * NPIX + n0 + wc * 64 + fj * 16 + cl] =
                    acc[fi][fj][r] + bias;
        }
}

// ---------------------------------------------------------------------------
extern "C" void kernel_launch(void* const* d_in, const int* in_sizes, int n_in,
                              void* d_out, int out_size, void* d_ws, size_t ws_size,
                              hipStream_t stream)
{
    const float* x     = (const float*)d_in[0];
    const float* w_qkv = (const float*)d_in[1];
    const float* w_out = (const float*)d_in[2];
    const float* b_out = (const float*)d_in[3];
    float* out = (float*)d_out;

    char* ws = (char*)d_ws;
    unsigned short* xp    = (unsigned short*)ws;                           // 32 MB
    unsigned short* WkF   = (unsigned short*)(ws + (64ull << 20));         // 256 KB
    unsigned short* WvF   = (unsigned short*)(ws + (64ull << 20) + (256u << 10));
    unsigned short* WqTF  = (unsigned short*)(ws + (64ull << 20) + (512u << 10));
    unsigned short* WoF   = (unsigned short*)(ws + (64ull << 20) + (768u << 10));
    float*          S     = (float*)(ws + (65ull << 20));                  // 8 KB
    float*          G     = (float*)(ws + (66ull << 20));                  // 2 MB
    unsigned short* AbarF = (unsigned short*)(ws + (68ull << 20));         // 256 KB
    unsigned short* F2    = (unsigned short*)(ws + (69ull << 20));         // 512 KB
    float*          Gp    = (float*)(ws + (72ull << 20));                  // 33.5 MB

    hipMemsetAsync(S, 0, 2048 * sizeof(float), stream);
    xp_convert<<<dim3(NPIX / 64, CIN / 64, NB), 256, 0, stream>>>(x, xp);
    wconv3<<<256, 256, 0, stream>>>(w_qkv, w_out, WkF, WvF, WqTF, WoF);
    kg_fused7<<<256, 512, 0, stream>>>(xp, WkF, Gp, S);
    g_reduce2<<<2048, 256, 0, stream>>>(Gp, G);
    c1_kernel<<<16, 256, 0, stream>>>(G, S, WvF, WqTF, AbarF);
    c2_kernel<<<dim3(4, NB), 256, 0, stream>>>(WoF, AbarF, F2);
    out_gemm4<<<dim3(NPIX / 128, CIN / 128, NB), 256, 0, stream>>>(xp, F2, b_out, out);
}

// Round 14
// 121.853 us; speedup vs baseline: 1.6727x; 1.0460x over previous
//
#include <hip/hip_runtime.h>
#include <hip/hip_bf16.h>

#define HEADS 4
#define DH    128
#define CIN   256
#define NPIX  16384
#define NB    4
#define HID   512

typedef __attribute__((ext_vector_type(8))) short bf16x8;
typedef __attribute__((ext_vector_type(4))) float f32x4;
typedef __attribute__((ext_vector_type(2))) unsigned u32x2;

__device__ __forceinline__ unsigned short f2bfu(float f) {
    union { __hip_bfloat16 h; unsigned short u; } cv;
    cv.h = __float2bfloat16(f);
    return cv.u;
}
__device__ __forceinline__ float bf2f(unsigned short u) {
    return __uint_as_float(((unsigned)u) << 16);
}

// ---- async global->LDS, 16B per lane --------------------------------------
typedef const __attribute__((address_space(1))) unsigned char* gas_t;
typedef __attribute__((address_space(3))) unsigned char* las_t;
__device__ __forceinline__ void glds16(const void* g, void* s) {
    __builtin_amdgcn_global_load_lds((gas_t)g, (las_t)s, 16, 0, 0);
}
__device__ __forceinline__ unsigned lds_off(const void* p) {
    return (unsigned)(size_t)(las_t)p;
}

// Frag-tile (weights/P/F): 16(row) x 32(k) bf16 = 512 ushorts, lane-major:
// element (row r, k) at us = (r + 16*(k>>3))*8 + (k&7).
// Plain tile (x): 16c x 16n = 256 ushorts, element (c,n) at us = (n&15)*16 + (c&15).

// ---------------------------------------------------------------------------
// K0a: x[b][c][n] fp32 -> xp plain tiles [b][n16 1024][c16 16][256]
// grid (256, 4, 4), block 256
// ---------------------------------------------------------------------------
__global__ __launch_bounds__(256) void xp_convert(const float* __restrict__ x,
                                                  unsigned short* __restrict__ xp)
{
    __shared__ float tile[64][67];
    const int b = blockIdx.z, c0 = blockIdx.y * 64, n0 = blockIdx.x * 64;
    const int t = threadIdx.x;
    const float* xb = x + ((size_t)b * CIN + c0) * NPIX + n0;
#pragma unroll
    for (int p = 0; p < 4; ++p) {
        const int c = p * 16 + (t >> 4);
        const int n = (t & 15) * 4;
        float4 v = *reinterpret_cast<const float4*>(xb + (size_t)c * NPIX + n);
        tile[c][n + 0] = v.x; tile[c][n + 1] = v.y;
        tile[c][n + 2] = v.z; tile[c][n + 3] = v.w;
    }
    __syncthreads();
    const int n16l = t >> 6, c16l = (t >> 4) & 3, n_loc = t & 15;
    unsigned short u16[16];
#pragma unroll
    for (int j = 0; j < 16; ++j)
        u16[j] = f2bfu(tile[c16l * 16 + j][n16l * 16 + n_loc]);
    unsigned short* dst = xp + (((size_t)(b * 1024 + (n0 >> 4) + n16l)) * 16
                                + (c0 >> 4) + c16l) * 256 + n_loc * 16;
    *reinterpret_cast<uint4*>(dst)     = *reinterpret_cast<const uint4*>(u16);
    *reinterpret_cast<uint4*>(dst + 8) = *reinterpret_cast<const uint4*>(u16 + 8);
}

// ---------------------------------------------------------------------------
// K0b: all weight frag tiles (unchanged).
// ---------------------------------------------------------------------------
__global__ __launch_bounds__(256) void wconv3(const float* __restrict__ w_qkv,
                                              const float* __restrict__ w_out,
                                              unsigned short* __restrict__ WkF,
                                              unsigned short* __restrict__ WvF,
                                              unsigned short* __restrict__ WqTF,
                                              unsigned short* __restrict__ WoF)
{
    const int t = threadIdx.x, lane = t & 63, wid = t >> 6;
    const int tile = blockIdx.x * 4 + wid;
    unsigned short u8[8];
    unsigned short* dst;
    if (tile < 256) {                       // WkF [h][d16 8][c32 8]
        const int h = tile >> 6, d16 = (tile >> 3) & 7, c32 = tile & 7;
        const float* src = w_qkv + (size_t)(512 + h * 128 + d16 * 16 + (lane & 15)) * CIN
                         + c32 * 32 + (lane >> 4) * 8;
#pragma unroll
        for (int j = 0; j < 8; ++j) u8[j] = f2bfu(src[j]);
        dst = WkF + (size_t)tile * 512 + lane * 8;
    } else if (tile < 512) {                // WvF [h][e16 8][c32 8]
        const int t2 = tile - 256;
        const int h = t2 >> 6, e16 = (t2 >> 3) & 7, c32 = t2 & 7;
        const float* src = w_qkv + (size_t)(1024 + h * 128 + e16 * 16 + (lane & 15)) * CIN
                         + c32 * 32 + (lane >> 4) * 8;
#pragma unroll
        for (int j = 0; j < 8; ++j) u8[j] = f2bfu(src[j]);
        dst = WvF + (size_t)t2 * 512 + lane * 8;
    } else if (tile < 768) {                // WqTF [h][c16 16][d32 4]
        const int t2 = tile - 512;
        const int h = t2 >> 6, c16 = (t2 >> 2) & 15, d32 = t2 & 3;
#pragma unroll
        for (int j = 0; j < 8; ++j)
            u8[j] = f2bfu(w_qkv[(size_t)(h * 128 + d32 * 32 + (lane >> 4) * 8 + j) * CIN
                                + c16 * 16 + (lane & 15)]);
        dst = WqTF + (size_t)t2 * 512 + lane * 8;
    } else {                                // WoF [o16 16][m32 16]
        const int t2 = tile - 768;
        const int o16 = t2 >> 4, m32 = t2 & 15;
        const float* src = w_out + (size_t)(o16 * 16 + (lane & 15)) * HID
                         + m32 * 32 + (lane >> 4) * 8;
#pragma unroll
        for (int j = 0; j < 8; ++j) u8[j] = f2bfu(src[j]);
        dst = WoF + (size_t)t2 * 512 + lane * 8;
    }
    *reinterpret_cast<uint4*>(dst) = *reinterpret_cast<const uint4*>(u8);
}

// ---------------------------------------------------------------------------
// K1: fused kg — 256-thread blocks (4 waves), 64 d x 1024 n each, grid 512
// -> 2 independent blocks/CU (LDS 72 KB).  Same verified phase structure:
// GEMM1 plain-tile ds_read_b128 B; GEMM2 ds_read_b64_tr_b16 B.  Gp in bf16.
// XCD remap co-locates the 8 (h,dh) blocks of each (ns,b) (identical x reads).
// ---------------------------------------------------------------------------
__global__ __launch_bounds__(256, 2) void kg_fused8(const unsigned short* __restrict__ xp,
                                                    const unsigned short* __restrict__ WkF,
                                                    unsigned short* __restrict__ Gp,
                                                    float* __restrict__ S)
{
    __shared__ unsigned short sX[2][64 * 256];   // 2 x 32 KB plain tiles [n16l 4][c16 16]
    __shared__ unsigned short sP[8 * 512];       // 8 KB frag tiles [d16l 4][n32 2]

    // remap: xcd = wgid&7 keyed to (ns,b) group -> all 8 (h,dh) siblings same XCD
    const int wgid = blockIdx.x;          // 0..511
    const int xcd  = wgid & 7;
    const int k_   = wgid >> 3;           // 0..63
    const int hd   = k_ & 7;              // h*2+dh
    const int gg   = k_ >> 3;             // 0..7
    const int h = hd >> 1, dh = hd & 1;
    const int g = xcd + 8 * gg;           // 0..63
    const int ns = g & 15, b = g >> 4;
    const int bh = b * 4 + h;

    const int t = threadIdx.x, lane = t & 63, w = t >> 6;   // 4 waves
    const int cl = lane & 15, q = lane >> 4, r0q = q * 4;
    const int boff = cl * 16 + (q & 1) * 8 + (q >> 1) * 256;
    const unsigned troff = (unsigned)((q >> 1) * 8192 + (q & 1) * 256 + cl * 8);

    // persistent Wk fragments: wave w owns d16 tile (h*8 + dh*4 + w): 32 VGPR
    bf16x8 aW[8];
#pragma unroll
    for (int ks = 0; ks < 8; ++ks)
        aW[ks] = *reinterpret_cast<const bf16x8*>(
            WkF + ((size_t)((h * 8 + dh * 4 + w) * 8 + ks)) * 512 + lane * 8);

    f32x4 accG[4][4] = {};
    float Sacc[4] = {};

    const unsigned short* xpb = xp + ((size_t)(b * 1024 + ns * 64) * 16) * 256;

#define STAGE(nt_, buf_)                                                        \
    {                                                                           \
        const unsigned short* src_ = xpb + (size_t)(nt_) * 16384;               \
        _Pragma("unroll")                                                       \
        for (int p = 0; p < 8; ++p)                                             \
            glds16(src_ + (size_t)p * 2048 + (size_t)t * 8,                     \
                   &sX[buf_][(size_t)p * 2048 + (size_t)w * 512]);              \
    }

    STAGE(0, 0);
    __syncthreads();

    int cur = 0;
    for (int nt = 0; nt < 16; ++nt) {
        if (nt < 15) STAGE(nt + 1, cur ^ 1);

        // ---- GEMM1: logits 16d x 64n per wave, K=256 ----
        f32x4 acc1[4] = {};
#pragma unroll
        for (int ks = 0; ks < 8; ++ks) {
            bf16x8 bb[4];
#pragma unroll
            for (int fj = 0; fj < 4; ++fj)
                bb[fj] = *reinterpret_cast<const bf16x8*>(
                    &sX[cur][(fj * 16 + 2 * ks) * 256 + boff]);
#pragma unroll
            for (int fj = 0; fj < 4; ++fj)
                acc1[fj] = __builtin_amdgcn_mfma_f32_16x16x32_bf16(
                    aW[ks], bb[fj], acc1[fj], 0, 0, 0);
        }

        // ---- exp -> sP (frag-tiled, tile (w, fj>>1)) + rowsum ----
#pragma unroll
        for (int fj = 0; fj < 4; ++fj)
#pragma unroll
            for (int r = 0; r < 4; ++r) {
                const float v = __expf(acc1[fj][r]);
                Sacc[r] += v;
                const int us = ((r0q + r) + 16 * ((fj & 1) * 2 + (cl >> 3))) * 8 + (cl & 7);
                sP[(w * 2 + (fj >> 1)) * 512 + us] = f2bfu(v);
            }
        __syncthreads();   // sP ready; nt+1 stages still in flight (vmcnt)

        // ---- GEMM2: G[64d x 64c] per wave (c16 tiles w*4..w*4+3) ----
        {
            const unsigned sx_base = lds_off(&sX[cur][0]);
#pragma unroll
            for (int kn = 0; kn < 2; ++kn) {
                u32x2 lo[4], hi[4];
#pragma unroll
                for (int fj = 0; fj < 4; ++fj) {
                    const int cc = w * 4 + fj;
                    const unsigned a = sx_base + (unsigned)((kn * 32 + cc) * 512) + troff;
                    asm volatile("ds_read_b64_tr_b16 %0, %2\n\t"
                                 "ds_read_b64_tr_b16 %1, %2 offset:128"
                                 : "=&v"(lo[fj]), "=&v"(hi[fj])
                                 : "v"(a));
                }
                asm volatile("s_waitcnt lgkmcnt(0)" ::: "memory");
                __builtin_amdgcn_sched_barrier(0);

                bf16x8 pa[4];
#pragma unroll
                for (int fi = 0; fi < 4; ++fi)
                    pa[fi] = *reinterpret_cast<const bf16x8*>(
                        &sP[(fi * 2 + kn) * 512 + lane * 8]);
#pragma unroll
                for (int fj = 0; fj < 4; ++fj) {
                    union { bf16x8 v; u32x2 h2[2]; } fb;
                    fb.h2[0] = lo[fj];
                    fb.h2[1] = hi[fj];
#pragma unroll
                    for (int fi = 0; fi < 4; ++fi)
                        accG[fi][fj] = __builtin_amdgcn_mfma_f32_16x16x32_bf16(
                            pa[fi], fb.v, accG[fi][fj], 0, 0, 0);
                }
            }
        }
        __syncthreads();   // drains nt+1 stages + WAR on sX bufs
        cur ^= 1;
    }
#undef STAGE

    // ---- S rowsums: row d = dh*64 + w*16 + r0q + r ----
#pragma unroll
    for (int r = 0; r < 4; ++r) {
        float v = Sacc[r];
        v += __shfl_xor(v, 1); v += __shfl_xor(v, 2);
        v += __shfl_xor(v, 4); v += __shfl_xor(v, 8);
        if (cl == 0)
            atomicAdd(&S[bh * 128 + dh * 64 + w * 16 + r0q + r], v);
    }

    // ---- Gp partial write (bf16, plain coalesced) ----
    unsigned short* gp = Gp + (size_t)(ns * 16 + bh) * 32768;
#pragma unroll
    for (int fi = 0; fi < 4; ++fi)
#pragma unroll
        for (int fj = 0; fj < 4; ++fj)
#pragma unroll
            for (int r = 0; r < 4; ++r)
                gp[(size_t)(dh * 64 + fi * 16 + r0q + r) * 256 + w * 64 + fj * 16 + cl]
                    = f2bfu(accG[fi][fj][r]);
}

// K2: G[bh][d][c] = sum over 16 bf16 partials (fp32 accumulate)
__global__ __launch_bounds__(256) void g_reduce2(const unsigned short* __restrict__ Gp,
                                                 float* __restrict__ G)
{
    const int idx = blockIdx.x * 256 + threadIdx.x;
    const int bh = idx >> 15, dc = idx & 32767;
    float s = 0.f;
#pragma unroll
    for (int k = 0; k < 16; ++k)
        s += bf2f(Gp[((size_t)k * 16 + bh) * 32768 + dc]);
    G[idx] = s;
}

// ---------------------------------------------------------------------------
// C1: per bh: ctx = (G/S) x Wv^T, then Abar = ctx^T x Wq -> AbarF frag tiles.
// ---------------------------------------------------------------------------
__global__ __launch_bounds__(256) void c1_kernel(const float* __restrict__ G,
                                                 const float* __restrict__ S,
                                                 const unsigned short* __restrict__ WvF,
                                                 const unsigned short* __restrict__ WqTF,
                                                 unsigned short* __restrict__ AbarF)
{
    __shared__ unsigned short sCtx[32 * 512];
    const int t = threadIdx.x, lane = t & 63, wid = t >> 6;
    const int bh = blockIdx.x, b = bh >> 2, h = bh & 3;
    const int cl = lane & 15, r0q = (lane >> 4) * 4;
    const int wr = wid >> 1, wc = wid & 1;
    const float* Gb = G + (size_t)bh * 32768;

    float invs[4];
#pragma unroll
    for (int fi = 0; fi < 4; ++fi)
        invs[fi] = 1.0f / S[bh * 128 + wr * 64 + fi * 16 + cl];

    f32x4 acc[4][4] = {};
#pragma unroll
    for (int ks = 0; ks < 8; ++ks) {
        bf16x8 a[4], bb[4];
#pragma unroll
        for (int fi = 0; fi < 4; ++fi) {
            const float* gp = Gb + (size_t)(wr * 64 + fi * 16 + cl) * 256
                            + ks * 32 + (lane >> 4) * 8;
            const float4 v0 = *reinterpret_cast<const float4*>(gp);
            const float4 v1 = *reinterpret_cast<const float4*>(gp + 4);
            unsigned short u8[8] = {
                f2bfu(v0.x * invs[fi]), f2bfu(v0.y * invs[fi]),
                f2bfu(v0.z * invs[fi]), f2bfu(v0.w * invs[fi]),
                f2bfu(v1.x * invs[fi]), f2bfu(v1.y * invs[fi]),
                f2bfu(v1.z * invs[fi]), f2bfu(v1.w * invs[fi]) };
            a[fi] = *reinterpret_cast<const bf16x8*>(u8);
        }
#pragma unroll
        for (int fj = 0; fj < 4; ++fj)
            bb[fj] = *reinterpret_cast<const bf16x8*>(
                WvF + ((size_t)(h * 8 + wc * 4 + fj) * 8 + ks) * 512 + lane * 8);
#pragma unroll
        for (int fi = 0; fi < 4; ++fi)
#pragma unroll
            for (int fj = 0; fj < 4; ++fj)
                acc[fi][fj] = __builtin_amdgcn_mfma_f32_16x16x32_bf16(
                    a[fi], bb[fj], acc[fi][fj], 0, 0, 0);
    }

#pragma unroll
    for (int fi = 0; fi < 4; ++fi)
#pragma unroll
        for (int fj = 0; fj < 4; ++fj)
#pragma unroll
            for (int r = 0; r < 4; ++r) {
                const int us = (cl + 16 * ((fi & 1) * 2 + ((r0q + r) >> 3))) * 8 + ((r0q + r) & 7);
                sCtx[((wc * 4 + fj) * 4 + wr * 2 + (fi >> 1)) * 512 + us] = f2bfu(acc[fi][fj][r]);
            }
    __syncthreads();

    const int we = wid >> 1, wcq = wid & 1;
    f32x4 acc2[4][8] = {};
#pragma unroll
    for (int ks = 0; ks < 4; ++ks) {
        bf16x8 a2[4], b2[8];
#pragma unroll
        for (int fi = 0; fi < 4; ++fi)
            a2[fi] = *reinterpret_cast<const bf16x8*>(
                &sCtx[((we * 4 + fi) * 4 + ks) * 512 + lane * 8]);
#pragma unroll
        for (int fj = 0; fj < 8; ++fj)
            b2[fj] = *reinterpret_cast<const bf16x8*>(
                WqTF + ((size_t)(h * 16 + wcq * 8 + fj) * 4 + ks) * 512 + lane * 8);
#pragma unroll
        for (int fi = 0; fi < 4; ++fi)
#pragma unroll
            for (int fj = 0; fj < 8; ++fj)
                acc2[fi][fj] = __builtin_amdgcn_mfma_f32_16x16x32_bf16(
                    a2[fi], b2[fj], acc2[fi][fj], 0, 0, 0);
    }

#pragma unroll
    for (int fi = 0; fi < 4; ++fi)
#pragma unroll
        for (int fj = 0; fj < 8; ++fj)
#pragma unroll
            for (int r = 0; r < 4; ++r) {
                const int c16 = wcq * 8 + fj;
                const int m32 = h * 4 + we * 2 + (fi >> 1);
                const int us  = (cl + 16 * ((fi & 1) * 2 + ((r0q + r) >> 3))) * 8 + ((r0q + r) & 7);
                AbarF[((size_t)(b * 16 + c16) * 16 + m32) * 512 + us] = f2bfu(acc2[fi][fj][r]);
            }
}

// ---------------------------------------------------------------------------
// C2: F[b][256o x 64c] = Wo x Abar (K=512), no LDS.
// ---------------------------------------------------------------------------
__global__ __launch_bounds__(256) void c2_kernel(const unsigned short* __restrict__ WoF,
                                                 const unsigned short* __restrict__ AbarF,
                                                 unsigned short* __restrict__ F2)
{
    const int t = threadIdx.x, lane = t & 63, wid = t >> 6;
    const int csp = blockIdx.x, b = blockIdx.y;
    const int cl = lane & 15, r0q = (lane >> 4) * 4;

    f32x4 acc[4][4] = {};
#pragma unroll
    for (int ks = 0; ks < 16; ++ks) {
        bf16x8 a[4], bb[4];
#pragma unroll
        for (int fi = 0; fi < 4; ++fi)
            a[fi] = *reinterpret_cast<const bf16x8*>(
                WoF + ((size_t)(wid * 4 + fi) * 16 + ks) * 512 + lane * 8);
#pragma unroll
        for (int fj = 0; fj < 4; ++fj)
            bb[fj] = *reinterpret_cast<const bf16x8*>(
                AbarF + ((size_t)(b * 16 + csp * 4 + fj) * 16 + ks) * 512 + lane * 8);
#pragma unroll
        for (int fi = 0; fi < 4; ++fi)
#pragma unroll
            for (int fj = 0; fj < 4; ++fj)
                acc[fi][fj] = __builtin_amdgcn_mfma_f32_16x16x32_bf16(
                    a[fi], bb[fj], acc[fi][fj], 0, 0, 0);
    }

#pragma unroll
    for (int fi = 0; fi < 4; ++fi)
#pragma unroll
        for (int fj = 0; fj < 4; ++fj)
#pragma unroll
            for (int r = 0; r < 4; ++r) {
                const int o16 = wid * 4 + fi;
                const int c32 = csp * 2 + (fj >> 1);
                const int us  = ((r0q + r) + 16 * ((fj & 1) * 2 + (cl >> 3))) * 8 + (cl & 7);
                F2[((size_t)(b * 16 + o16) * 8 + c32) * 512 + us] = f2bfu(acc[fi][fj][r]);
            }
}

// ---------------------------------------------------------------------------
// K6: out GEMM.  Stage whole xp n-panel (64 KB = 128 tiles) once; F2 from L2.
// grid (128, 2, 4), block 256 (2x2 waves of 64o x 64n)
// ---------------------------------------------------------------------------
__global__ __launch_bounds__(256, 2) void out_gemm4(const unsigned short* __restrict__ xp,
                                                    const unsigned short* __restrict__ F2,
                                                    const float* __restrict__ b_out,
                                                    float* __restrict__ out)
{
    __shared__ unsigned short sXT[128 * 256];   // 64 KB: [8 n16][16 c16] plain tiles
    const int t = threadIdx.x, lane = t & 63, wid = t >> 6;
    const int n0 = blockIdx.x * 128, m0 = blockIdx.y * 128, b = blockIdx.z;
    const int wr = wid >> 1, wc = wid & 1;
    const int cl = lane & 15, q = lane >> 4;
    const int boff = cl * 16 + (q & 1) * 8 + (q >> 1) * 256;

    const unsigned short* src = xp + ((size_t)(b * 1024 + (n0 >> 4)) * 16) * 256;
#pragma unroll
    for (int p = 0; p < 16; ++p)
        glds16(src + ((size_t)p * 256 + t) * 8, &sXT[((size_t)p * 256 + wid * 64) * 8]);
    __syncthreads();

    f32x4 acc[4][4] = {};
#pragma unroll
    for (int ks = 0; ks < 8; ++ks) {
        bf16x8 a[4], bb[4];
#pragma unroll
        for (int fi = 0; fi < 4; ++fi)
            a[fi] = *reinterpret_cast<const bf16x8*>(
                F2 + (((size_t)b * 16 + (m0 >> 4) + wr * 4 + fi) * 8 + ks) * 512 + lane * 8);
#pragma unroll
        for (int fj = 0; fj < 4; ++fj)
            bb[fj] = *reinterpret_cast<const bf16x8*>(
                &sXT[((wc * 4 + fj) * 16 + 2 * ks) * 256 + boff]);
#pragma unroll
        for (int fi = 0; fi < 4; ++fi)
#pragma unroll
            for (int fj = 0; fj < 4; ++fj)
                acc[fi][fj] = __builtin_amdgcn_mfma_f32_16x16x32_bf16(
                    a[fi], bb[fj], acc[fi][fj], 0, 0, 0);
    }

    const int r0q = q * 4;
#pragma unroll
    for (int fi = 0; fi < 4; ++fi)
#pragma unroll
        for (int r = 0; r < 4; ++r) {
            const int o = m0 + wr * 64 + fi * 16 + r0q + r;
            const float bias = b_out[o];
#pragma unroll
            for (int fj = 0; fj < 4; ++fj)
                out[((size_t)b * CIN + o) * NPIX + n0 + wc * 64 + fj * 16 + cl] =
                    acc[fi][fj][r] + bias;
        }
}

// ---------------------------------------------------------------------------
extern "C" void kernel_launch(void* const* d_in, const int* in_sizes, int n_in,
                              void* d_out, int out_size, void* d_ws, size_t ws_size,
                              hipStream_t stream)
{
    const float* x     = (const float*)d_in[0];
    const float* w_qkv = (const float*)d_in[1];
    const float* w_out = (const float*)d_in[2];
    const float* b_out = (const float*)d_in[3];
    float* out = (float*)d_out;

    char* ws = (char*)d_ws;
    unsigned short* xp    = (unsigned short*)ws;                           // 32 MB
    unsigned short* WkF   = (unsigned short*)(ws + (64ull << 20));         // 256 KB
    unsigned short* WvF   = (unsigned short*)(ws + (64ull << 20) + (256u << 10));
    unsigned short* WqTF  = (unsigned short*)(ws + (64ull << 20) + (512u << 10));
    unsigned short* WoF   = (unsigned short*)(ws + (64ull << 20) + (768u << 10));
    float*          S     = (float*)(ws + (65ull << 20));                  // 8 KB
    float*          G     = (float*)(ws + (66ull << 20));                  // 2 MB
    unsigned short* AbarF = (unsigned short*)(ws + (68ull << 20));         // 256 KB
    unsigned short* F2    = (unsigned short*)(ws + (69ull << 20));         // 512 KB
    unsigned short* Gp    = (unsigned short*)(ws + (72ull << 20));         // 16.75 MB (bf16)

    hipMemsetAsync(S, 0, 2048 * sizeof(float), stream);
    xp_convert<<<dim3(NPIX / 64, CIN / 64, NB), 256, 0, stream>>>(x, xp);
    wconv3<<<256, 256, 0, stream>>>(w_qkv, w_out, WkF, WvF, WqTF, WoF);
    kg_fused8<<<512, 256, 0, stream>>>(xp, WkF, Gp, S);
    g_reduce2<<<2048, 256, 0, stream>>>(Gp, G);
    c1_kernel<<<16, 256, 0, stream>>>(G, S, WvF, WqTF, AbarF);
    c2_kernel<<<dim3(4, NB), 256, 0, stream>>>(WoF, AbarF, F2);
    out_gemm4<<<dim3(NPIX / 128, CIN / 128, NB), 256, 0, stream>>>(xp, F2, b_out, out);
}